// Round 1
// baseline (14660.236 us; speedup 1.0000x reference)
//
// T-LSTM persistent-recurrence kernel for MI355X (gfx950).
//
// Design (round 1, correctness-first):
//  - prep kernel: W,U -> WUt[2048][768] bf16 (B^T layout, k-contiguous),
//    W_d -> Wdt[512][512] bf16; zeroes sync flags.
//  - recurrence kernel: 128 persistent WGs = 4 independent batch groups
//    (32 rows) x 32 col-WGs (16 hidden cols each). Weights live in LDS
//    (~116 KB/WG) for all 512 steps. One device-scope flag barrier per
//    group per step. mfma_f32_16x16x32_bf16, fp32 c master state.

#include <hip/hip_runtime.h>

typedef unsigned short u16;
typedef __attribute__((ext_vector_type(8))) short short8;
typedef __attribute__((ext_vector_type(4))) float f32x4;

constexpr int BATCH = 128, SEQ = 512, ISZ = 256, HSZ = 512, G4H = 2048;
constexpr int KZ   = ISZ + HSZ;              // 768: [x;h] concat K
constexpr int NGRP = 4,  MR  = BATCH / NGRP; // 32 rows per group
constexpr int NCW  = 32, CPW = HSZ / NCW;    // 32 col-WGs, 16 cols each
constexpr int LDBZ = KZ + 8, LDBC = HSZ + 8; // LDS row pads (16B-aligned)
constexpr int BH   = BATCH * HSZ;            // 65536
constexpr size_t BSH = (size_t)BATCH * SEQ * HSZ;

// workspace layout (bytes)
constexpr size_t WUT_OFF = 0;                                  // 2048*768*2
constexpr size_t WDT_OFF = WUT_OFF + (size_t)G4H * KZ * 2;     // 512*512*2
constexpr size_t HBF_OFF = WDT_OFF + (size_t)HSZ * HSZ * 2;    // h bf16 x2
constexpr size_t CBF_OFF = HBF_OFF + (size_t)2 * BH * 2;       // c bf16 x2
constexpr size_t CF_OFF  = CBF_OFF + (size_t)2 * BH * 2;       // c fp32 x2
constexpr size_t FLG_OFF = CF_OFF  + (size_t)2 * BH * 4;       // 256 ints
constexpr size_t WS_NEED = FLG_OFF + 256 * 4;                  // ~4.5 MB

constexpr int LDS_BYTES = (64 * LDBZ + 16 * LDBC) * 2 + 10 * 256 * 4; // 126208

__device__ __forceinline__ u16 f2bf(float f) {
  unsigned u = __float_as_uint(f);
  u += 0x7fffu + ((u >> 16) & 1u);   // RNE
  return (u16)(u >> 16);
}

__device__ __forceinline__ short8 ld_f2bf8(const float* p) {
  float4 a = *(const float4*)p;
  float4 b = *(const float4*)(p + 4);
  short8 r;
  r[0] = (short)f2bf(a.x); r[1] = (short)f2bf(a.y);
  r[2] = (short)f2bf(a.z); r[3] = (short)f2bf(a.w);
  r[4] = (short)f2bf(b.x); r[5] = (short)f2bf(b.y);
  r[6] = (short)f2bf(b.z); r[7] = (short)f2bf(b.w);
  return r;
}

__device__ __forceinline__ float sig_f(float x)  { return 1.f / (1.f + __expf(-x)); }
__device__ __forceinline__ float tanh_f(float x) { return 1.f - 2.f / (1.f + __expf(2.f * x)); }

__global__ void tlstm_prep(const float* __restrict__ W, const float* __restrict__ U,
                           const float* __restrict__ Wd,
                           u16* __restrict__ wut, u16* __restrict__ wdt,
                           int* __restrict__ flags) {
  const int total1 = G4H * KZ;     // WUt elements
  const int total2 = HSZ * HSZ;    // Wdt elements
  int i = blockIdx.x * blockDim.x + threadIdx.x;
  if (i < 256) flags[i] = 0;       // deterministic sync state every launch
  if (i < total1) {
    int j = i / KZ, k = i - j * KZ;
    float v = (k < ISZ) ? W[(size_t)k * G4H + j] : U[(size_t)(k - ISZ) * G4H + j];
    wut[i] = f2bf(v);
  } else if (i < total1 + total2) {
    int ii = i - total1;
    int j = ii / HSZ, k = ii - j * HSZ;
    wdt[ii] = f2bf(Wd[(size_t)k * HSZ + j]);
  }
}

__global__ void __launch_bounds__(320, 1)
tlstm_rec(const float* __restrict__ x, const float* __restrict__ dtp,
          const float* __restrict__ bias, const float* __restrict__ bd,
          const u16* __restrict__ wut, const u16* __restrict__ wdt,
          u16* hbf, u16* cbf, float* cf, int* flags, float* out) {
  extern __shared__ char lds[];
  u16*   Bz = (u16*)lds;                                      // [64][LDBZ]
  u16*   Bc = Bz + 64 * LDBZ;                                 // [16][LDBC]
  float* zs = (float*)(lds + (64 * LDBZ + 16 * LDBC) * 2);    // [10][16][16]

  const int tid  = threadIdx.x;
  const int grp  = blockIdx.x >> 5;     // batch group 0..3
  const int cwg  = blockIdx.x & 31;     // column WG 0..31
  const int G0   = grp * MR;            // first batch row of group
  const int C0   = cwg * CPW;           // first hidden col of WG
  const int wave = tid >> 6, lane = tid & 63;
  const int m16  = lane & 15, quad = lane >> 4;

  // ---- stage weights into LDS (once) ----
  {
    const unsigned* src = (const unsigned*)wut;
    unsigned* dst = (unsigned*)Bz;
    for (int i = tid; i < 64 * (KZ / 2); i += 320) {
      int gc = i / (KZ / 2), d = i - gc * (KZ / 2);
      int zc = (gc >> 4) * HSZ + C0 + (gc & 15);   // gate-major z column
      dst[gc * (LDBZ / 2) + d] = src[zc * (KZ / 2) + d];
    }
    const unsigned* s2 = (const unsigned*)wdt;
    unsigned* d2 = (unsigned*)Bc;
    for (int i = tid; i < 16 * (HSZ / 2); i += 320) {
      int r = i >> 8, d = i & 255;
      d2[r * (LDBC / 2) + d] = s2[(C0 + r) * (HSZ / 2) + d];
    }
  }
  // ---- zero group's own state rows (redundant across col-WGs: benign) ----
  {
    unsigned* h0 = (unsigned*)hbf;
    unsigned* c0 = (unsigned*)cbf;
    for (int i = tid; i < MR * HSZ / 2; i += 320) {
      int off = (G0 * HSZ) / 2 + i;
      h0[off] = 0u; c0[off] = 0u;
    }
    for (int i = tid; i < MR * HSZ; i += 320) cf[G0 * HSZ + i] = 0.f;
  }
  __syncthreads();

  for (int t = 0; t < SEQ; ++t) {
    const int p = t & 1, q = p ^ 1;
    const u16* hA = hbf + (size_t)p * BH;
    const u16* cA = cbf + (size_t)p * BH;

    if (wave < 4) {
      // gate wave: z[:, gate*H + C0..C0+16) for rows G0..G0+32
      const int g = wave;
      f32x4 acc0 = {0.f, 0.f, 0.f, 0.f}, acc1 = {0.f, 0.f, 0.f, 0.f};
      const int r0 = G0 + m16, r1 = G0 + 16 + m16;
      const u16* bzrow = Bz + (size_t)(g * 16 + m16) * LDBZ + quad * 8;
      const float* x0 = x + ((size_t)r0 * SEQ + t) * ISZ + quad * 8;
      const float* x1 = x + ((size_t)r1 * SEQ + t) * ISZ + quad * 8;
#pragma unroll
      for (int kt = 0; kt < 8; ++kt) {            // K 0..255: x @ W
        short8 a0 = ld_f2bf8(x0 + kt * 32);
        short8 a1 = ld_f2bf8(x1 + kt * 32);
        short8 b  = *(const short8*)(bzrow + kt * 32);
        acc0 = __builtin_amdgcn_mfma_f32_16x16x32_bf16(a0, b, acc0, 0, 0, 0);
        acc1 = __builtin_amdgcn_mfma_f32_16x16x32_bf16(a1, b, acc1, 0, 0, 0);
      }
      const u16* h0p = hA + (size_t)r0 * HSZ + quad * 8;
      const u16* h1p = hA + (size_t)r1 * HSZ + quad * 8;
#pragma unroll
      for (int kt = 0; kt < 16; ++kt) {           // K 256..767: h @ U
        short8 a0 = *(const short8*)(h0p + kt * 32);
        short8 a1 = *(const short8*)(h1p + kt * 32);
        short8 b  = *(const short8*)(bzrow + 256 + kt * 32);
        acc0 = __builtin_amdgcn_mfma_f32_16x16x32_bf16(a0, b, acc0, 0, 0, 0);
        acc1 = __builtin_amdgcn_mfma_f32_16x16x32_bf16(a1, b, acc1, 0, 0, 0);
      }
#pragma unroll
      for (int i = 0; i < 4; ++i) {
        zs[(g * 2 + 0) * 256 + (quad * 4 + i) * 16 + m16] = acc0[i];
        zs[(g * 2 + 1) * 256 + (quad * 4 + i) * 16 + m16] = acc1[i];
      }
    } else {
      // c_s wave: (c @ W_d)[:, C0..C0+16)
      f32x4 acc0 = {0.f, 0.f, 0.f, 0.f}, acc1 = {0.f, 0.f, 0.f, 0.f};
      const int r0 = G0 + m16, r1 = G0 + 16 + m16;
      const u16* c0p = cA + (size_t)r0 * HSZ + quad * 8;
      const u16* c1p = cA + (size_t)r1 * HSZ + quad * 8;
      const u16* bcrow = Bc + (size_t)m16 * LDBC + quad * 8;
#pragma unroll
      for (int kt = 0; kt < 16; ++kt) {
        short8 a0 = *(const short8*)(c0p + kt * 32);
        short8 a1 = *(const short8*)(c1p + kt * 32);
        short8 b  = *(const short8*)(bcrow + kt * 32);
        acc0 = __builtin_amdgcn_mfma_f32_16x16x32_bf16(a0, b, acc0, 0, 0, 0);
        acc1 = __builtin_amdgcn_mfma_f32_16x16x32_bf16(a1, b, acc1, 0, 0, 0);
      }
#pragma unroll
      for (int i = 0; i < 4; ++i) {
        zs[(8 + 0) * 256 + (quad * 4 + i) * 16 + m16] = acc0[i];
        zs[(8 + 1) * 256 + (quad * 4 + i) * 16 + m16] = acc1[i];
      }
    }
    __syncthreads();

    // ---- element-wise T-LSTM update for this WG's 32 rows x 16 cols ----
    for (int e = tid; e < MR * CPW; e += 320) {
      const int ms = e >> 8, rc = e & 255;
      const int row = G0 + ms * 16 + (rc >> 4);
      const int ch  = C0 + (rc & 15);
      float zi = zs[(0 * 2 + ms) * 256 + rc] + bias[ch];
      float zf = zs[(1 * 2 + ms) * 256 + rc] + bias[HSZ + ch];
      float zo = zs[(2 * 2 + ms) * 256 + rc] + bias[2 * HSZ + ch];
      float zc = zs[(3 * 2 + ms) * 256 + rc] + bias[3 * HSZ + ch];
      float s  = zs[(8 + ms) * 256 + rc] + bd[ch];
      float cprev = cf[(size_t)p * BH + (size_t)row * HSZ + ch];
      float dt = dtp[(size_t)row * SEQ + t];
      float cs = tanh_f(s);
      float gdec = 1.f / logf(2.718281828459045f + dt);
      float cadj = cprev - cs + cs * gdec;
      float ig = sig_f(zi), fg = sig_f(zf), og = sig_f(zo);
      float ct = tanh_f(zc);
      float cnew = fg * cadj + ig * ct;
      float hnew = og * tanh_f(cnew);
      cf [(size_t)q * BH + (size_t)row * HSZ + ch] = cnew;
      cbf[(size_t)q * BH + (size_t)row * HSZ + ch] = f2bf(cnew);
      hbf[(size_t)q * BH + (size_t)row * HSZ + ch] = f2bf(hnew);
      out[((size_t)row * SEQ + t) * HSZ + ch] = hnew;
      if (t == SEQ - 1) {
        out[BSH + (size_t)row * HSZ + ch] = hnew;         // h_t
        out[BSH + BH + (size_t)row * HSZ + ch] = cnew;    // c_t
      }
    }

    // ---- per-group barrier (device-scope flags) ----
    if (t < SEQ - 1) {
      __threadfence();        // each wave drains+publishes its own stores
      __syncthreads();
      if (tid == 0)
        __hip_atomic_store(&flags[grp * 64 + cwg], t + 2,
                           __ATOMIC_RELEASE, __HIP_MEMORY_SCOPE_AGENT);
      if (wave == 0) {
        int* f = &flags[grp * 64 + (lane & 31)];
        while (__hip_atomic_load(f, __ATOMIC_ACQUIRE,
                                 __HIP_MEMORY_SCOPE_AGENT) < t + 2)
          __builtin_amdgcn_s_sleep(2);
      }
      __syncthreads();
    }
  }
}

extern "C" void kernel_launch(void* const* d_in, const int* in_sizes, int n_in,
                              void* d_out, int out_size, void* d_ws, size_t ws_size,
                              hipStream_t stream) {
  (void)in_sizes; (void)n_in; (void)out_size; (void)ws_size;
  const float* x  = (const float*)d_in[0];
  const float* dt = (const float*)d_in[1];
  const float* W  = (const float*)d_in[2];
  const float* U  = (const float*)d_in[3];
  const float* b  = (const float*)d_in[4];
  const float* Wd = (const float*)d_in[5];
  const float* bd = (const float*)d_in[6];
  float* out = (float*)d_out;
  char*  ws  = (char*)d_ws;

  u16*   wut   = (u16*)(ws + WUT_OFF);
  u16*   wdt   = (u16*)(ws + WDT_OFF);
  u16*   hbf   = (u16*)(ws + HBF_OFF);
  u16*   cbf   = (u16*)(ws + CBF_OFF);
  float* cf    = (float*)(ws + CF_OFF);
  int*   flags = (int*)(ws + FLG_OFF);

  tlstm_prep<<<7168, 256, 0, stream>>>(W, U, Wd, wut, wdt, flags);

  hipFuncSetAttribute((const void*)tlstm_rec,
                      hipFuncAttributeMaxDynamicSharedMemorySize, LDS_BYTES);
  tlstm_rec<<<NGRP * NCW, 320, LDS_BYTES, stream>>>(
      x, dt, b, bd, wut, wdt, hbf, cbf, cf, flags, out);
}

// Round 2
// 3926.028 us; speedup vs baseline: 3.7341x; 3.7341x over previous
//
// T-LSTM persistent-recurrence kernel for MI355X (gfx950) — round 2.
//
// Round 1 post-mortem: 28.6 us/step, 925 MB HBM fetch -> per-step
// __threadfence/acquire fences flush per-XCD L2 (wb/inv) every step for
// every WG, destroying all cache locality and serializing on HBM latency.
//
// Round 2: fence-free handshake. All cross-WG state (h,c bf16) and flags
// use RELAXED agent-scope atomics (bypass non-coherent L2, coherent at
// MALL/L3). Ordering: producer stores drain (vmcnt 0) at the pre-flag
// __syncthreads before the flag store issues; consumer loads issue after
// the spin breaks (in-order HW issue + compiler barriers). No wb/inv ops
// anywhere in the steady-state loop.
//  - 8 batch groups x 16 rows x 32 col-WGs = 256 WGs (1/CU).
//  - weights persistent in LDS; h-tile staged to LDS once/step (kills 4x
//    redundant gate-wave reads); c_s GEMM + x-part GEMM overlap staging.
//  - fp32 c master state in LDS (WG-private); biases in LDS.

#include <hip/hip_runtime.h>

typedef unsigned short u16;
typedef unsigned int u32;
typedef unsigned long long u64;
typedef __attribute__((ext_vector_type(8))) short short8;
typedef __attribute__((ext_vector_type(4))) float f32x4;

constexpr int BATCH = 128, SEQ = 512, ISZ = 256, HSZ = 512, G4H = 2048;
constexpr int KZ   = ISZ + HSZ;                 // 768
constexpr int NGRP = 8,  MR  = BATCH / NGRP;    // 16 rows per group
constexpr int NCW  = 32, CPW = HSZ / NCW;       // 16 cols per WG
constexpr int LDBZ = KZ + 8, LDBC = HSZ + 8, LDH = HSZ + 8;
constexpr int BH   = BATCH * HSZ;               // 65536
constexpr size_t BSH = (size_t)BATCH * SEQ * HSZ;

// workspace layout (bytes)
constexpr size_t WUT_OFF = 0;                                  // 2048*768*2
constexpr size_t WDT_OFF = WUT_OFF + (size_t)G4H * KZ * 2;     // 512*512*2
constexpr size_t HBF_OFF = WDT_OFF + (size_t)HSZ * HSZ * 2;    // h bf16 x2
constexpr size_t CBF_OFF = HBF_OFF + (size_t)2 * BH * 2;       // c bf16 x2
constexpr size_t FLG_OFF = CBF_OFF + (size_t)2 * BH * 2;       // 256 ints

// LDS layout (bytes)
constexpr int BZ_OFF  = 0;                       // [64][LDBZ] u16
constexpr int BC_OFF  = BZ_OFF  + 64 * LDBZ * 2; // [16][LDBC] u16
constexpr int HS_OFF  = BC_OFF  + 16 * LDBC * 2; // [MR][LDH]  u16
constexpr int ZS_OFF  = HS_OFF  + MR * LDH * 2;  // [5][16][16] f32
constexpr int CFL_OFF = ZS_OFF  + 5 * 256 * 4;   // [16][16] f32
constexpr int BL_OFF  = CFL_OFF + MR * CPW * 4;  // [5][16] f32
constexpr int LDS_BYTES = BL_OFF + 5 * CPW * 4;  // 139072

__device__ __forceinline__ u16 f2bf(float f) {
  unsigned u = __float_as_uint(f);
  u += 0x7fffu + ((u >> 16) & 1u);   // RNE
  return (u16)(u >> 16);
}

__device__ __forceinline__ short8 ld_f2bf8(const float* p) {
  float4 a = *(const float4*)p;
  float4 b = *(const float4*)(p + 4);
  short8 r;
  r[0] = (short)f2bf(a.x); r[1] = (short)f2bf(a.y);
  r[2] = (short)f2bf(a.z); r[3] = (short)f2bf(a.w);
  r[4] = (short)f2bf(b.x); r[5] = (short)f2bf(b.y);
  r[6] = (short)f2bf(b.z); r[7] = (short)f2bf(b.w);
  return r;
}

__device__ __forceinline__ u64 ld_at64(const void* p) {
  return __hip_atomic_load((const u64*)p, __ATOMIC_RELAXED,
                           __HIP_MEMORY_SCOPE_AGENT);
}
__device__ __forceinline__ void st_at64(void* p, u64 v) {
  __hip_atomic_store((u64*)p, v, __ATOMIC_RELAXED, __HIP_MEMORY_SCOPE_AGENT);
}
__device__ __forceinline__ void st_at32(void* p, u32 v) {
  __hip_atomic_store((u32*)p, v, __ATOMIC_RELAXED, __HIP_MEMORY_SCOPE_AGENT);
}
__device__ __forceinline__ short8 ld_bf8_at(const u16* p) {
  union { u64 u[2]; short8 s; } v;
  v.u[0] = ld_at64(p);
  v.u[1] = ld_at64(p + 4);
  return v.s;
}

__device__ __forceinline__ float sig_f(float x)  { return 1.f / (1.f + __expf(-x)); }
__device__ __forceinline__ float tanh_f(float x) { return 1.f - 2.f / (1.f + __expf(2.f * x)); }

__global__ void tlstm_prep(const float* __restrict__ W, const float* __restrict__ U,
                           const float* __restrict__ Wd,
                           u16* __restrict__ wut, u16* __restrict__ wdt,
                           int* __restrict__ flags) {
  const int total1 = G4H * KZ;
  const int total2 = HSZ * HSZ;
  int i = blockIdx.x * blockDim.x + threadIdx.x;
  if (i < 256) flags[i] = 0;       // deterministic sync state every launch
  if (i < total1) {
    int j = i / KZ, k = i - j * KZ;
    float v = (k < ISZ) ? W[(size_t)k * G4H + j] : U[(size_t)(k - ISZ) * G4H + j];
    wut[i] = f2bf(v);
  } else if (i < total1 + total2) {
    int ii = i - total1;
    int j = ii / HSZ, k = ii - j * HSZ;
    wdt[ii] = f2bf(Wd[(size_t)k * HSZ + j]);
  }
}

__global__ void __launch_bounds__(320, 1)
tlstm_rec(const float* __restrict__ x, const float* __restrict__ dtp,
          const float* __restrict__ bias, const float* __restrict__ bd,
          const u16* __restrict__ wut, const u16* __restrict__ wdt,
          u16* hbf, u16* cbf, int* flags, float* out) {
  extern __shared__ char lds[];
  u16*   Bz  = (u16*)(lds + BZ_OFF);
  u16*   Bc  = (u16*)(lds + BC_OFF);
  u16*   hs  = (u16*)(lds + HS_OFF);
  float* zs  = (float*)(lds + ZS_OFF);
  float* cfl = (float*)(lds + CFL_OFF);
  float* bl  = (float*)(lds + BL_OFF);

  const int tid  = threadIdx.x;
  const int grp  = blockIdx.x >> 5;     // batch group 0..7
  const int cwg  = blockIdx.x & 31;     // column WG 0..31
  const int G0   = grp * MR;
  const int C0   = cwg * CPW;
  const int wave = tid >> 6, lane = tid & 63;
  const int m16  = lane & 15, quad = lane >> 4;

  // ---- stage weights into LDS (once) ----
  {
    const unsigned* src = (const unsigned*)wut;
    unsigned* dst = (unsigned*)Bz;
    for (int i = tid; i < 64 * (KZ / 2); i += 320) {
      int gc = i / (KZ / 2), d = i - gc * (KZ / 2);
      int zc = (gc >> 4) * HSZ + C0 + (gc & 15);   // gate-major z column
      dst[gc * (LDBZ / 2) + d] = src[zc * (KZ / 2) + d];
    }
    const unsigned* s2 = (const unsigned*)wdt;
    unsigned* d2 = (unsigned*)Bc;
    for (int i = tid; i < 16 * (HSZ / 2); i += 320) {
      int r = i >> 8, d = i & 255;
      d2[r * (LDBC / 2) + d] = s2[(C0 + r) * (HSZ / 2) + d];
    }
  }
  // biases -> LDS
  if (tid < 80) {
    int j = tid >> 4, c = tid & 15;
    bl[tid] = (j < 4) ? bias[j * HSZ + C0 + c] : bd[C0 + c];
  }
  // fp32 c master (WG-private) -> zero
  if (tid < 256) cfl[tid] = 0.f;
  // zero group's state rows in buffer 0 (relaxed agent atomics; all col-WGs
  // of a group write the same zeros — benign)
  {
    u64* h0 = (u64*)(hbf + (size_t)G0 * HSZ);
    u64* c0 = (u64*)(cbf + (size_t)G0 * HSZ);
    for (int i = tid; i < MR * HSZ / 4; i += 320) {
      st_at64(h0 + i, 0ull);
      st_at64(c0 + i, 0ull);
    }
  }
  __syncthreads();   // drains vmcnt: zeros are at L3 before t=0 reads

  const int* fbase = flags + grp * 32;

  for (int t = 0; t < SEQ; ++t) {
    const int p = t & 1, q = p ^ 1;
    const u16* hA = hbf + (size_t)p * BH;
    const u16* cA = cbf + (size_t)p * BH;
    u16* hQ = hbf + (size_t)q * BH;
    u16* cQ = cbf + (size_t)q * BH;

    f32x4 acc = {0.f, 0.f, 0.f, 0.f};

    // ---- stage h tile (16 rows x 512 bf16) into LDS, de-duplicated ----
    {
      const u64* src = (const u64*)(hA + (size_t)G0 * HSZ);
      u64* dst = (u64*)hs;
      for (int i = tid; i < MR * HSZ / 4; i += 320) {
        int r = i >> 7, k = i & 127;
        dst[r * (LDH / 4) + k] =
            __hip_atomic_load(src + r * 128 + k, __ATOMIC_RELAXED,
                              __HIP_MEMORY_SCOPE_AGENT);
      }
    }

    // ---- work that does NOT need hs, overlapped with staging ----
    if (wave < 4) {
      // gate wave g: x_t @ W part (K 0..255)
      const int g = wave;
      const u16* bz = Bz + (size_t)(g * 16 + m16) * LDBZ + quad * 8;
      const float* xp = x + ((size_t)(G0 + m16) * SEQ + t) * ISZ + quad * 8;
#pragma unroll
      for (int kt = 0; kt < 8; ++kt) {
        short8 a = ld_f2bf8(xp + kt * 32);
        short8 b = *(const short8*)(bz + kt * 32);
        acc = __builtin_amdgcn_mfma_f32_16x16x32_bf16(a, b, acc, 0, 0, 0);
      }
    } else {
      // c_s wave: full (c @ W_d)[:, C0..C0+16) — independent of hs
      const u16* cp = cA + (size_t)(G0 + m16) * HSZ + quad * 8;
      const u16* bc = Bc + (size_t)m16 * LDBC + quad * 8;
#pragma unroll
      for (int kt = 0; kt < 16; ++kt) {
        short8 a = ld_bf8_at(cp + kt * 32);
        short8 b = *(const short8*)(bc + kt * 32);
        acc = __builtin_amdgcn_mfma_f32_16x16x32_bf16(a, b, acc, 0, 0, 0);
      }
#pragma unroll
      for (int i = 0; i < 4; ++i)
        zs[4 * 256 + (quad * 4 + i) * 16 + m16] = acc[i];
    }
    __syncthreads();   // hs staged

    if (wave < 4) {
      // gate wave g: h @ U part (K 256..767) from LDS
      const int g = wave;
      const u16* bz = Bz + (size_t)(g * 16 + m16) * LDBZ + 256 + quad * 8;
      const u16* hp = hs + (size_t)m16 * LDH + quad * 8;
#pragma unroll
      for (int kt = 0; kt < 16; ++kt) {
        short8 a = *(const short8*)(hp + kt * 32);
        short8 b = *(const short8*)(bz + kt * 32);
        acc = __builtin_amdgcn_mfma_f32_16x16x32_bf16(a, b, acc, 0, 0, 0);
      }
#pragma unroll
      for (int i = 0; i < 4; ++i)
        zs[g * 256 + (quad * 4 + i) * 16 + m16] = acc[i];
    }
    __syncthreads();   // zs complete

    // ---- element-wise T-LSTM update: 16 rows x 16 cols, col-pairs ----
    if (tid < 128) {
      const int lr = tid >> 3;          // local row 0..15
      const int cp2 = (tid & 7) * 2;    // even local col
      const int row = G0 + lr;
      const float dt = dtp[(size_t)row * SEQ + t];
      const float gdec = 1.f / logf(2.718281828459045f + dt);
      float rh[2], rc[2];
#pragma unroll
      for (int u = 0; u < 2; ++u) {
        const int c = cp2 + u;
        const int zb = lr * 16 + c;
        float zi = zs[0 * 256 + zb] + bl[0 * 16 + c];
        float zf = zs[1 * 256 + zb] + bl[1 * 16 + c];
        float zo = zs[2 * 256 + zb] + bl[2 * 16 + c];
        float zc = zs[3 * 256 + zb] + bl[3 * 16 + c];
        float s  = zs[4 * 256 + zb] + bl[4 * 16 + c];
        float cprev = cfl[zb];
        float cs = tanh_f(s);
        float cadj = cprev - cs + cs * gdec;
        float ig = sig_f(zi), fg = sig_f(zf), og = sig_f(zo);
        float ct = tanh_f(zc);
        float cnew = fg * cadj + ig * ct;
        float hnew = og * tanh_f(cnew);
        cfl[zb] = cnew;
        rh[u] = hnew; rc[u] = cnew;
      }
      const int ch = C0 + cp2;
      st_at32(hQ + (size_t)row * HSZ + ch,
              (u32)f2bf(rh[0]) | ((u32)f2bf(rh[1]) << 16));
      st_at32(cQ + (size_t)row * HSZ + ch,
              (u32)f2bf(rc[0]) | ((u32)f2bf(rc[1]) << 16));
      float2 hv; hv.x = rh[0]; hv.y = rh[1];
      *(float2*)(out + ((size_t)row * SEQ + t) * HSZ + ch) = hv;
      if (t == SEQ - 1) {
        float2 cv; cv.x = rc[0]; cv.y = rc[1];
        *(float2*)(out + BSH + (size_t)row * HSZ + ch) = hv;       // h_t
        *(float2*)(out + BSH + BH + (size_t)row * HSZ + ch) = cv;  // c_t
      }
    }

    // ---- fence-free per-group barrier ----
    if (t < SEQ - 1) {
      __syncthreads();   // all threads' state stores drained (vmcnt 0)
      __asm__ volatile("" ::: "memory");
      if (tid == 0)
        __hip_atomic_store(&flags[grp * 32 + cwg], t + 2,
                           __ATOMIC_RELAXED, __HIP_MEMORY_SCOPE_AGENT);
      for (;;) {
        int v = (lane < 32)
                    ? __hip_atomic_load(fbase + lane, __ATOMIC_RELAXED,
                                        __HIP_MEMORY_SCOPE_AGENT)
                    : 0x7fffffff;
        if (__all(v >= t + 2)) break;
        __builtin_amdgcn_s_sleep(2);
      }
      __asm__ volatile("" ::: "memory");
    }
  }
}

extern "C" void kernel_launch(void* const* d_in, const int* in_sizes, int n_in,
                              void* d_out, int out_size, void* d_ws, size_t ws_size,
                              hipStream_t stream) {
  (void)in_sizes; (void)n_in; (void)out_size; (void)ws_size;
  const float* x  = (const float*)d_in[0];
  const float* dt = (const float*)d_in[1];
  const float* W  = (const float*)d_in[2];
  const float* U  = (const float*)d_in[3];
  const float* b  = (const float*)d_in[4];
  const float* Wd = (const float*)d_in[5];
  const float* bd = (const float*)d_in[6];
  float* out = (float*)d_out;
  char*  ws  = (char*)d_ws;

  u16* wut   = (u16*)(ws + WUT_OFF);
  u16* wdt   = (u16*)(ws + WDT_OFF);
  u16* hbf   = (u16*)(ws + HBF_OFF);
  u16* cbf   = (u16*)(ws + CBF_OFF);
  int* flags = (int*)(ws + FLG_OFF);

  tlstm_prep<<<7168, 256, 0, stream>>>(W, U, Wd, wut, wdt, flags);

  hipFuncSetAttribute((const void*)tlstm_rec,
                      hipFuncAttributeMaxDynamicSharedMemorySize, LDS_BYTES);
  tlstm_rec<<<NGRP * NCW, 320, LDS_BYTES, stream>>>(
      x, dt, b, bd, wut, wdt, hbf, cbf, flags, out);
}